// Round 1
// baseline (158.646 us; speedup 1.0000x reference)
//
#include <hip/hip_runtime.h>
#include <hip/hip_bf16.h>

// Sizes (fixed by the problem)
#define DD   512
#define SS   8
#define BBATCH 16
#define TT   1024
#define BT   16384      // B*T
#define KK1  4096       // S*D
#define NN1  1024       // 2*D

typedef __attribute__((ext_vector_type(8))) short bf16x8;
typedef __attribute__((ext_vector_type(4))) float f32x4;

__device__ __forceinline__ float bf2f(unsigned short u) {
    union { unsigned int i; float f; } c; c.i = ((unsigned int)u) << 16; return c.f;
}
__device__ __forceinline__ unsigned short f2bf(float f) {
    union { float f; unsigned int i; } c; c.f = f;
    unsigned int x = c.i;
    x += 0x7fffu + ((x >> 16) & 1u);   // round-to-nearest-even
    return (unsigned short)(x >> 16);
}

// async global->LDS, 16B per lane; lptr must be wave-uniform, gptr per-lane
#define GLOAD_LDS16(gp, lp) \
    __builtin_amdgcn_global_load_lds((const __attribute__((address_space(1))) void*)(gp), \
                                     (__attribute__((address_space(3))) void*)(lp), 16, 0, 0)

// ---------------- conversions ----------------

// x (f32, BT*D) -> bf16, vectorized 4/thread
__global__ void k_conv_x(const float* __restrict__ x, unsigned short* __restrict__ xbf) {
    int gid = blockIdx.x * 256 + threadIdx.x;          // 2,097,152 threads
    float4 v = ((const float4*)x)[gid];
    ushort4 o;
    o.x = f2bf(v.x); o.y = f2bf(v.y); o.z = f2bf(v.z); o.w = f2bf(v.w);
    ((ushort4*)xbf)[gid] = o;
}

// Abf[i][k] = bf16(m1_w[i, e*8+s]) with k = s*512+e  (512 x 4096), 2 k per thread
__global__ void k_conv_A(const float* __restrict__ m1w, unsigned int* __restrict__ Abf2) {
    int gid = blockIdx.x * 256 + threadIdx.x;          // 1,048,576 threads
    int i  = gid >> 11;
    int k2 = (gid & 2047) << 1;                         // even k; pair stays in same s
    int s = k2 >> 9, e = k2 & 511;
    const float* row = m1w + (size_t)i * 4096;
    unsigned int lo = f2bf(row[e * 8 + s]);
    unsigned int hi = f2bf(row[e * 8 + 8 + s]);
    Abf2[gid] = lo | (hi << 16);
}

// WT[j][k] = bf16(W_ent[k*1024 + j])  (transpose 4096x1024 -> 1024x4096), LDS tiles
__global__ void k_conv_W(const float* __restrict__ W, unsigned short* __restrict__ WT) {
    __shared__ float tile[32][33];
    int k0 = blockIdx.x * 32, j0 = blockIdx.y * 32;
    int tx = threadIdx.x & 31, ty = threadIdx.x >> 5;  // 8 rows at a time
    #pragma unroll
    for (int r = ty; r < 32; r += 8)
        tile[r][tx] = W[(size_t)(k0 + r) * 1024 + j0 + tx];
    __syncthreads();
    #pragma unroll
    for (int r = ty; r < 32; r += 8)
        WT[(size_t)(j0 + r) * 4096 + k0 + tx] = f2bf(tile[tx][r]);
}

// ---------------- small reductions ----------------

// sum over t of x -> sumx[b][d] (atomic partials; sumx pre-zeroed)
__global__ void k_sumx(const float* __restrict__ x, float* __restrict__ sumx) {
    int b = blockIdx.x, tc = blockIdx.y;
    int tid = threadIdx.x;
    const float* xp = x + ((size_t)b * 1024 + tc * 64) * 512;
    float a0 = 0.f, a1 = 0.f;
    for (int t = 0; t < 64; ++t) {
        a0 += xp[(size_t)t * 512 + tid];
        a1 += xp[(size_t)t * 512 + tid + 256];
    }
    atomicAdd(&sumx[b * 512 + tid], a0);
    atomicAdd(&sumx[b * 512 + tid + 256], a1);
}

// bias2[i] = sum_c m1_w[i,c] * b_ent[(c&7)*512 + (c>>3)]   (c = e*8+s)
__global__ void k_bias2(const float* __restrict__ m1w, const float* __restrict__ bent,
                        float* __restrict__ bias2) {
    int i = blockIdx.x, tid = threadIdx.x;
    const float* row = m1w + (size_t)i * 4096;
    float acc = 0.f;
    for (int c = tid; c < 4096; c += 256) {
        int e = c >> 3, s = c & 7;
        acc += row[c] * bent[s * 512 + e];
    }
    for (int off = 32; off; off >>= 1) acc += __shfl_xor(acc, off);
    __shared__ float r4[4];
    if ((tid & 63) == 0) r4[tid >> 6] = acc;
    __syncthreads();
    if (tid == 0) bias2[i] = r4[0] + r4[1] + r4[2] + r4[3];
}

// cb[b][i] = (1/T) * sum_d sumx[b][d]*M2t[d][i] + bias2[i] + m1_b[i]
__global__ void k_cb(const float* __restrict__ sumx, const unsigned short* __restrict__ M2t,
                     const float* __restrict__ bias2, const float* __restrict__ m1b,
                     float* __restrict__ cbo) {
    int b = blockIdx.x;
    int i = blockIdx.y * 256 + threadIdx.x;
    const float* sx = sumx + b * 512;
    float acc = 0.f;
    #pragma unroll 8
    for (int d = 0; d < 512; ++d)
        acc += sx[d] * bf2f(M2t[(size_t)d * 512 + i]);
    cbo[b * 512 + i] = acc * (1.0f / 1024.0f) + bias2[i] + m1b[i];
}

// ---------------- GEMM1: C1[i,j] = sum_k Abf[i,k]*W[k,j]; writes M1bf (left half,
// row-major) and M2t (right half, transposed) ----------------
__launch_bounds__(256)
__global__ void k_gemm1(const unsigned short* __restrict__ Abf,
                        const unsigned short* __restrict__ WT,
                        unsigned short* __restrict__ M1bf,
                        unsigned short* __restrict__ M2t) {
    __shared__ __align__(16) unsigned short sA[64 * 32];   // [row][k]
    __shared__ __align__(16) unsigned short sB[64 * 32];   // [j][k]
    int i0 = blockIdx.x * 64, j0 = blockIdx.y * 64;
    int tid = threadIdx.x, lane = tid & 63, w = tid >> 6;  // 4 waves
    int wm = w & 1, wn = w >> 1;                           // wave -> 32x32 quadrant
    int srow = lane >> 2, scol = (lane & 3) * 8;
    const unsigned short* gA = Abf + (size_t)(i0 + w * 16 + srow) * 4096 + scol;
    const unsigned short* gB = WT  + (size_t)(j0 + w * 16 + srow) * 4096 + scol;
    unsigned short* lA = sA + w * 16 * 32;
    unsigned short* lB = sB + w * 16 * 32;
    f32x4 acc[2][2] = {};
    int lo = lane & 15, hi8 = (lane >> 4) * 8;
    for (int k0 = 0; k0 < 4096; k0 += 32) {
        if (k0) __syncthreads();
        GLOAD_LDS16(gA + k0, lA);
        GLOAD_LDS16(gB + k0, lB);
        __syncthreads();
        bf16x8 a0 = *(const bf16x8*)(sA + (wm * 32 +      lo) * 32 + hi8);
        bf16x8 a1 = *(const bf16x8*)(sA + (wm * 32 + 16 + lo) * 32 + hi8);
        bf16x8 b0 = *(const bf16x8*)(sB + (wn * 32 +      lo) * 32 + hi8);
        bf16x8 b1 = *(const bf16x8*)(sB + (wn * 32 + 16 + lo) * 32 + hi8);
        acc[0][0] = __builtin_amdgcn_mfma_f32_16x16x32_bf16(a0, b0, acc[0][0], 0, 0, 0);
        acc[0][1] = __builtin_amdgcn_mfma_f32_16x16x32_bf16(a0, b1, acc[0][1], 0, 0, 0);
        acc[1][0] = __builtin_amdgcn_mfma_f32_16x16x32_bf16(a1, b0, acc[1][0], 0, 0, 0);
        acc[1][1] = __builtin_amdgcn_mfma_f32_16x16x32_bf16(a1, b1, acc[1][1], 0, 0, 0);
    }
    int hi = lane >> 4;
    bool left = (j0 < 512);
    #pragma unroll
    for (int m = 0; m < 2; ++m) {
        int ib = i0 + wm * 32 + m * 16 + hi * 4;
        #pragma unroll
        for (int n = 0; n < 2; ++n) {
            int j = j0 + wn * 32 + n * 16 + lo;
            f32x4 v = acc[m][n];
            if (left) {
                #pragma unroll
                for (int r = 0; r < 4; ++r)
                    M1bf[(size_t)(ib + r) * 512 + j] = f2bf(v[0 + r]);
            } else {
                ushort4 p;
                p.x = f2bf(v[0]); p.y = f2bf(v[1]); p.z = f2bf(v[2]); p.w = f2bf(v[3]);
                *(ushort4*)(M2t + (size_t)(j - 512) * 512 + ib) = p;
            }
        }
    }
}

// ---------------- GEMM2 + fused LN/tanh/logit ----------------
// y[bt,i] = sum_d xbf[bt,d]*M1bf[i,d] + cb[b,i]; LN over i; tanh; logit = h . m2w + m2b
__launch_bounds__(512)
__global__ void k_gemm2(const unsigned short* __restrict__ xbf,
                        const unsigned short* __restrict__ M1bf,
                        const float* __restrict__ cb,
                        const float* __restrict__ lng, const float* __restrict__ lnb,
                        const float* __restrict__ m2w, const float* __restrict__ m2b,
                        float* __restrict__ logits) {
    __shared__ __align__(16) unsigned short sA[32 * 32];    // x tile [row][k]
    __shared__ __align__(16) unsigned short sB[512 * 32];   // M1 tile [i][k]
    __shared__ float sStat[2][8][32];
    __shared__ float sMu[32], sRs[32];
    __shared__ float sLp[8][32];
    int bt0 = blockIdx.x * 32;
    int b = bt0 >> 10;
    int tid = threadIdx.x, lane = tid & 63, w = tid >> 6;   // 8 waves
    int srow = lane >> 2, scol = (lane & 3) * 8;
    int lo = lane & 15, hi = lane >> 4, hi8 = hi * 8;
    f32x4 acc[2][4] = {};
    for (int k0 = 0; k0 < 512; k0 += 32) {
        if (k0) __syncthreads();
        #pragma unroll
        for (int q = 0; q < 4; ++q) {
            int r0 = (w * 4 + q) * 16;
            GLOAD_LDS16(M1bf + (size_t)(r0 + srow) * 512 + k0 + scol, sB + r0 * 32);
        }
        if (w < 2) {
            GLOAD_LDS16(xbf + (size_t)(bt0 + w * 16 + srow) * 512 + k0 + scol, sA + w * 16 * 32);
        }
        __syncthreads();
        bf16x8 af[2], bfr[4];
        af[0] = *(const bf16x8*)(sA + (     lo) * 32 + hi8);
        af[1] = *(const bf16x8*)(sA + (16 + lo) * 32 + hi8);
        #pragma unroll
        for (int n = 0; n < 4; ++n)
            bfr[n] = *(const bf16x8*)(sB + (w * 64 + n * 16 + lo) * 32 + hi8);
        #pragma unroll
        for (int m = 0; m < 2; ++m)
            #pragma unroll
            for (int n = 0; n < 4; ++n)
                acc[m][n] = __builtin_amdgcn_mfma_f32_16x16x32_bf16(af[m], bfr[n], acc[m][n], 0, 0, 0);
    }
    // add cb (per-column, per-batch)
    #pragma unroll
    for (int n = 0; n < 4; ++n) {
        float cbv = cb[b * 512 + w * 64 + n * 16 + lo];
        #pragma unroll
        for (int m = 0; m < 2; ++m)
            #pragma unroll
            for (int r = 0; r < 4; ++r)
                acc[m][n][r] += cbv;
    }
    // row stats: partial over this wave's 64 cols, reduced over the 16-lane row group
    #pragma unroll
    for (int m = 0; m < 2; ++m) {
        #pragma unroll
        for (int r = 0; r < 4; ++r) {
            float s1 = 0.f, s2 = 0.f;
            #pragma unroll
            for (int n = 0; n < 4; ++n) { float t = acc[m][n][r]; s1 += t; s2 += t * t; }
            #pragma unroll
            for (int msk = 1; msk < 16; msk <<= 1) {
                s1 += __shfl_xor(s1, msk);
                s2 += __shfl_xor(s2, msk);
            }
            if (lo == 0) {
                int row = m * 16 + hi * 4 + r;
                sStat[0][w][row] = s1;
                sStat[1][w][row] = s2;
            }
        }
    }
    __syncthreads();
    if (tid < 32) {
        float s1 = 0.f, s2 = 0.f;
        #pragma unroll
        for (int ww = 0; ww < 8; ++ww) { s1 += sStat[0][ww][tid]; s2 += sStat[1][ww][tid]; }
        float mu = s1 * (1.0f / 512.0f);
        float var = s2 * (1.0f / 512.0f) - mu * mu;
        sMu[tid] = mu;
        sRs[tid] = rsqrtf(var + 1e-5f);
    }
    __syncthreads();
    float gv[4], bv[4], wv[4];
    #pragma unroll
    for (int n = 0; n < 4; ++n) {
        int c = w * 64 + n * 16 + lo;
        gv[n] = lng[c]; bv[n] = lnb[c]; wv[n] = m2w[c];
    }
    #pragma unroll
    for (int m = 0; m < 2; ++m) {
        #pragma unroll
        for (int r = 0; r < 4; ++r) {
            int row = m * 16 + hi * 4 + r;
            float mu = sMu[row], rs = sRs[row];
            float lg = 0.f;
            #pragma unroll
            for (int n = 0; n < 4; ++n) {
                float h = tanhf((acc[m][n][r] - mu) * rs * gv[n] + bv[n]);
                lg += h * wv[n];
            }
            #pragma unroll
            for (int msk = 1; msk < 16; msk <<= 1) lg += __shfl_xor(lg, msk);
            if (lo == 0) sLp[w][row] = lg;
        }
    }
    __syncthreads();
    if (tid < 32) {
        float lg = 0.f;
        #pragma unroll
        for (int ww = 0; ww < 8; ++ww) lg += sLp[ww][tid];
        logits[bt0 + tid] = lg + m2b[0];
    }
}

// ---------------- softmax over T and context ----------------
__global__ void k_softmax(const float* __restrict__ logits, float* __restrict__ wout) {
    int b = blockIdx.x, tid = threadIdx.x;   // 256 threads, 4 t each
    __shared__ float red[4];
    float4 v = ((const float4*)(logits + b * 1024))[tid];
    float mx = fmaxf(fmaxf(v.x, v.y), fmaxf(v.z, v.w));
    for (int off = 32; off; off >>= 1) mx = fmaxf(mx, __shfl_xor(mx, off));
    if ((tid & 63) == 0) red[tid >> 6] = mx;
    __syncthreads();
    mx = fmaxf(fmaxf(red[0], red[1]), fmaxf(red[2], red[3]));
    float e0 = expf(v.x - mx), e1 = expf(v.y - mx), e2 = expf(v.z - mx), e3 = expf(v.w - mx);
    float sm = e0 + e1 + e2 + e3;
    for (int off = 32; off; off >>= 1) sm += __shfl_xor(sm, off);
    __syncthreads();
    if ((tid & 63) == 0) red[tid >> 6] = sm;
    __syncthreads();
    float inv = 1.0f / (red[0] + red[1] + red[2] + red[3]);
    float4 o; o.x = e0 * inv; o.y = e1 * inv; o.z = e2 * inv; o.w = e3 * inv;
    ((float4*)(wout + b * 1024))[tid] = o;
}

// context[b][d] = sum_t w[b][t] * x[b][t][d]  (atomic partials; ctx pre-zeroed)
__global__ void k_context(const float* __restrict__ x, const float* __restrict__ wts,
                          float* __restrict__ ctx) {
    int b = blockIdx.x, tc = blockIdx.y;
    int tid = threadIdx.x;
    const float* xp = x + ((size_t)b * 1024 + tc * 64) * 512;
    const float* wp = wts + b * 1024 + tc * 64;
    float a0 = 0.f, a1 = 0.f;
    for (int t = 0; t < 64; ++t) {
        float wv = wp[t];
        a0 += wv * xp[(size_t)t * 512 + tid];
        a1 += wv * xp[(size_t)t * 512 + tid + 256];
    }
    atomicAdd(&ctx[b * 512 + tid], a0);
    atomicAdd(&ctx[b * 512 + tid + 256], a1);
}

// ---------------- launch ----------------
extern "C" void kernel_launch(void* const* d_in, const int* in_sizes, int n_in,
                              void* d_out, int out_size, void* d_ws, size_t ws_size,
                              hipStream_t stream) {
    (void)in_sizes; (void)n_in; (void)out_size; (void)ws_size;
    const float* x    = (const float*)d_in[0];
    const float* Went = (const float*)d_in[1];
    const float* bent = (const float*)d_in[2];
    const float* m1w  = (const float*)d_in[3];
    const float* m1b  = (const float*)d_in[4];
    const float* lng  = (const float*)d_in[5];
    const float* lnb  = (const float*)d_in[6];
    const float* m2w  = (const float*)d_in[7];
    const float* m2b  = (const float*)d_in[8];
    float* out = (float*)d_out;            // [0,8192): context ; [8192,24576): attn
    char* ws = (char*)d_ws;

    unsigned short* Abf   = (unsigned short*)(ws);                        // 4 MB
    unsigned short* WT    = (unsigned short*)(ws + 4194304);              // 8 MB
    unsigned short* xbf   = (unsigned short*)(ws + 12582912);             // 16 MB
    unsigned short* M1bf  = (unsigned short*)(ws + 29360128);             // 512 KB
    unsigned short* M2t   = (unsigned short*)(ws + 29884416);             // 512 KB
    float* sumx   = (float*)(ws + 30408704);                              // 32 KB
    float* bias2  = (float*)(ws + 30441472);                              // 2 KB
    float* cb     = (float*)(ws + 30443520);                              // 32 KB
    float* logits = (float*)(ws + 30476288);                              // 64 KB

    hipMemsetAsync(sumx, 0, 512 * BBATCH * sizeof(float), stream);
    hipMemsetAsync(out, 0, 8192 * sizeof(float), stream);

    k_conv_x<<<8192, 256, 0, stream>>>(x, xbf);
    k_conv_A<<<4096, 256, 0, stream>>>(m1w, (unsigned int*)Abf);
    k_conv_W<<<dim3(128, 32), 256, 0, stream>>>(Went, WT);
    k_sumx<<<dim3(16, 16), 256, 0, stream>>>(x, sumx);
    k_bias2<<<512, 256, 0, stream>>>(m1w, bent, bias2);
    k_gemm1<<<dim3(8, 16), 256, 0, stream>>>(Abf, WT, M1bf, M2t);
    k_cb<<<dim3(16, 2), 256, 0, stream>>>(sumx, M2t, bias2, m1b, cb);
    k_gemm2<<<512, 512, 0, stream>>>(xbf, M1bf, cb, lng, lnb, m2w, m2b, logits);
    k_softmax<<<16, 256, 0, stream>>>(logits, out + 8192);
    k_context<<<dim3(16, 16), 256, 0, stream>>>(x, out + 8192, out);
}

// Round 2
// 93.734 us; speedup vs baseline: 1.6925x; 1.6925x over previous
//
#include <hip/hip_runtime.h>
#include <hip/hip_bf16.h>

typedef __attribute__((ext_vector_type(8))) short bf16x8;
typedef __attribute__((ext_vector_type(4))) float f32x4;

__device__ __forceinline__ float bf2f(unsigned short u) {
    union { unsigned int i; float f; } c; c.i = ((unsigned int)u) << 16; return c.f;
}
__device__ __forceinline__ unsigned short f2bf(float f) {
    union { float f; unsigned int i; } c; c.f = f;
    unsigned int x = c.i;
    x += 0x7fffu + ((x >> 16) & 1u);   // round-to-nearest-even
    return (unsigned short)(x >> 16);
}
__device__ __forceinline__ float tanh_fast(float v) {
    float a = fabsf(v);
    a = fminf(a, 15.0f);
    float e = __expf(2.0f * a);
    float t = 1.0f - 2.0f / (e + 1.0f);
    return copysignf(t, v);
}

// async global->LDS, 16B per lane; lptr must be wave-uniform, gptr per-lane
#define GLOAD_LDS16(gp, lp) \
    __builtin_amdgcn_global_load_lds((const __attribute__((address_space(1))) void*)(gp), \
                                     (__attribute__((address_space(3))) void*)(lp), 16, 0, 0)

#define MFMA(a, b, c) __builtin_amdgcn_mfma_f32_16x16x32_bf16((a), (b), (c), 0, 0, 0)

// ---------------- small reductions ----------------

// sum over t of x -> sumx[b][d] (atomic partials; sumx pre-zeroed)
__global__ void k_sumx(const float* __restrict__ x, float* __restrict__ sumx) {
    int b = blockIdx.x, tc = blockIdx.y;
    int tid = threadIdx.x;
    const float* xp = x + ((size_t)b * 1024 + tc * 64) * 512;
    float a0 = 0.f, a1 = 0.f;
    for (int t = 0; t < 64; ++t) {
        a0 += xp[(size_t)t * 512 + tid];
        a1 += xp[(size_t)t * 512 + tid + 256];
    }
    atomicAdd(&sumx[b * 512 + tid], a0);
    atomicAdd(&sumx[b * 512 + tid + 256], a1);
}

// Abf[i][k] = bf16(m1w[i][k]) (natural order; K index k = e*8+s), fused with
// bias2[i] = sum_k m1w[i,k] * b_ent[(k&7)*512 + (k>>3)]
__global__ void k_prepA(const float* __restrict__ m1w, const float* __restrict__ bent,
                        unsigned short* __restrict__ Abf, float* __restrict__ bias2) {
    int i = blockIdx.x, tid = threadIdx.x;
    const float* row = m1w + (size_t)i * 4096;
    float acc = 0.f;
    #pragma unroll
    for (int q = 0; q < 4; ++q) {
        int col = q * 1024 + tid * 4;
        float4 v = *(const float4*)(row + col);
        ushort4 o;
        o.x = f2bf(v.x); o.y = f2bf(v.y); o.z = f2bf(v.z); o.w = f2bf(v.w);
        *(ushort4*)(Abf + (size_t)i * 4096 + col) = o;
        int e0 = col >> 3, s0 = col & 7;   // col % 4 == 0, so s0 in {0,4}; no e crossing
        acc += v.x * bent[(s0    ) * 512 + e0];
        acc += v.y * bent[(s0 + 1) * 512 + e0];
        acc += v.z * bent[(s0 + 2) * 512 + e0];
        acc += v.w * bent[(s0 + 3) * 512 + e0];
    }
    #pragma unroll
    for (int off = 32; off; off >>= 1) acc += __shfl_xor(acc, off);
    __shared__ float r4[4];
    if ((tid & 63) == 0) r4[tid >> 6] = acc;
    __syncthreads();
    if (tid == 0) bias2[i] = r4[0] + r4[1] + r4[2] + r4[3];
}

// WT[j][k] = bf16(W_ent[(k&7)*512 + (k>>3)][j]); k = e*8+s
__global__ void k_conv_W(const float* __restrict__ W, unsigned short* __restrict__ WT) {
    __shared__ float tile[128][33];
    int e0 = blockIdx.x * 16;
    int j0 = blockIdx.y * 32;
    int tid = threadIdx.x;
    int tx = tid & 31, ty = tid >> 5;
    #pragma unroll
    for (int q = 0; q < 16; ++q) {
        int lk = q * 8 + ty;              // local k = de*8+s, 0..127
        int de = lk >> 3, s = lk & 7;
        int r = s * 512 + e0 + de;
        tile[lk][tx] = W[(size_t)r * 1024 + j0 + tx];
    }
    __syncthreads();
    int j = tid >> 3, ck = (tid & 7) * 16;
    unsigned short* dst = WT + (size_t)(j0 + j) * 4096 + e0 * 8 + ck;
    #pragma unroll
    for (int g = 0; g < 4; ++g) {
        ushort4 o;
        o.x = f2bf(tile[ck + g * 4 + 0][j]);
        o.y = f2bf(tile[ck + g * 4 + 1][j]);
        o.z = f2bf(tile[ck + g * 4 + 2][j]);
        o.w = f2bf(tile[ck + g * 4 + 3][j]);
        *(ushort4*)(dst + g * 4) = o;
    }
}

// ---------------- GEMM1 (split-K=8): C[i,j] = sum_k Abf[i,k] WT[j,k] ----------------
// tile 64x256, 8 waves (2m x 4n), BK=64, XOR-swizzled LDS.
// left j-tiles (by<2) store C partials; right (by>=2) store C^T partials (swapped mfma).
__launch_bounds__(512, 2)
__global__ void k_gemm1(const unsigned short* __restrict__ Abf,
                        const unsigned short* __restrict__ WT,
                        float* __restrict__ CpL, float* __restrict__ CpR) {
    __shared__ __align__(16) unsigned short sA[64 * 64];
    __shared__ __align__(16) unsigned short sB[256 * 64];
    int i0 = blockIdx.x * 64;
    int j0 = blockIdx.y * 256;
    int kbase = blockIdx.z * 512;
    int tid = threadIdx.x, lane = tid & 63, w = tid >> 6;
    int wm = w >> 2, wn = w & 3;
    int lr = lane >> 3, sl = lane & 7;
    int lo = lane & 15, hi = lane >> 4;
    int arow = w * 8 + lr;  // arow&7 == lr
    const unsigned short* gA = Abf + (size_t)(i0 + arow) * 4096 + kbase + ((sl ^ lr) << 3);
    unsigned short* dA = sA + w * 8 * 64;
    const unsigned short* gB[4]; unsigned short* dB[4];
    #pragma unroll
    for (int g = 0; g < 4; ++g) {
        int brow = w * 32 + g * 8 + lr;   // brow&7 == lr
        gB[g] = WT + (size_t)(j0 + brow) * 4096 + kbase + ((sl ^ lr) << 3);
        dB[g] = sB + (w * 32 + g * 8) * 64;
    }
    bool left = (blockIdx.y < 2);
    f32x4 acc[2][4] = {};
    for (int k0 = 0; k0 < 512; k0 += 64) {
        if (k0) __syncthreads();
        GLOAD_LDS16(gA + k0, dA);
        #pragma unroll
        for (int g = 0; g < 4; ++g) GLOAD_LDS16(gB[g] + k0, dB[g]);
        __syncthreads();
        #pragma unroll
        for (int kk = 0; kk < 2; ++kk) {
            int slotX = ((kk * 4 + hi) ^ (lo & 7)) << 3;
            bf16x8 a0 = *(const bf16x8*)(sA + (wm * 32 +      lo) * 64 + slotX);
            bf16x8 a1 = *(const bf16x8*)(sA + (wm * 32 + 16 + lo) * 64 + slotX);
            #pragma unroll
            for (int n = 0; n < 4; ++n) {
                bf16x8 bb = *(const bf16x8*)(sB + (wn * 64 + n * 16 + lo) * 64 + slotX);
                if (left) {
                    acc[0][n] = MFMA(a0, bb, acc[0][n]);
                    acc[1][n] = MFMA(a1, bb, acc[1][n]);
                } else {
                    acc[0][n] = MFMA(bb, a0, acc[0][n]);
                    acc[1][n] = MFMA(bb, a1, acc[1][n]);
                }
            }
        }
    }
    int ksoff = blockIdx.z * 262144;
    if (left) {
        #pragma unroll
        for (int m = 0; m < 2; ++m) {
            int ib = i0 + wm * 32 + m * 16 + hi * 4;
            #pragma unroll
            for (int n = 0; n < 4; ++n) {
                int j = j0 + wn * 64 + n * 16 + lo;
                #pragma unroll
                for (int r = 0; r < 4; ++r)
                    CpL[ksoff + (ib + r) * 512 + j] = acc[m][n][r];
            }
        }
    } else {
        #pragma unroll
        for (int m = 0; m < 2; ++m) {
            int ic = i0 + wm * 32 + m * 16 + lo;
            #pragma unroll
            for (int n = 0; n < 4; ++n) {
                int db = j0 - 512 + wn * 64 + n * 16 + hi * 4;
                #pragma unroll
                for (int r = 0; r < 4; ++r)
                    CpR[ksoff + (db + r) * 512 + ic] = acc[m][n][r];
            }
        }
    }
}

// sum 8 split-K partials -> bf16 (used for M1bf and M2t)
__global__ void k_reduce8(const float* __restrict__ Cp, unsigned short* __restrict__ outbf) {
    int gid = blockIdx.x * 256 + threadIdx.x;   // 65536 threads x 4 elems
    float4 s = ((const float4*)Cp)[gid];
    #pragma unroll
    for (int ks = 1; ks < 8; ++ks) {
        float4 t = ((const float4*)Cp)[ks * 65536 + gid];
        s.x += t.x; s.y += t.y; s.z += t.z; s.w += t.w;
    }
    ushort4 o;
    o.x = f2bf(s.x); o.y = f2bf(s.y); o.z = f2bf(s.z); o.w = f2bf(s.w);
    ((ushort4*)outbf)[gid] = o;
}

// cb[b][i] = (1/T) * sum_d sumx[b][d]*M2t[d][i] + bias2[i] + m1b[i]
__global__ void k_cb(const float* __restrict__ sumx, const unsigned short* __restrict__ M2t,
                     const float* __restrict__ bias2, const float* __restrict__ m1b,
                     float* __restrict__ cbo) {
    int b = blockIdx.x, i0 = blockIdx.y * 64;
    int tid = threadIdx.x;
    int il = tid & 63, dq = tid >> 6;
    const float* sx = sumx + b * 512 + dq * 128;
    const unsigned short* mp = M2t + (size_t)dq * 128 * 512 + i0 + il;
    float acc = 0.f;
    #pragma unroll 4
    for (int dd = 0; dd < 128; ++dd)
        acc += sx[dd] * bf2f(mp[(size_t)dd * 512]);
    __shared__ float sPart[4][64];
    sPart[dq][il] = acc;
    __syncthreads();
    if (tid < 64) {
        float v = sPart[0][tid] + sPart[1][tid] + sPart[2][tid] + sPart[3][tid];
        cbo[b * 512 + i0 + tid] = v * (1.0f / 1024.0f) + bias2[i0 + tid] + m1b[i0 + tid];
    }
}

// ---------------- GEMM2 + fused LN/tanh/logit ----------------
// y[bt,i] = sum_d x[bt,d]*M1[i,d] + cb[b,i]; LN over i; tanh; logit = h . m2w + m2b
// tile 64 x 512(full N), 8 waves (2m x 4n), BK=64; A reg-staged from f32 x (fused convert).
__launch_bounds__(512, 2)
__global__ void k_gemm2(const float* __restrict__ x,
                        const unsigned short* __restrict__ M1bf,
                        const float* __restrict__ cb,
                        const float* __restrict__ lng, const float* __restrict__ lnb,
                        const float* __restrict__ m2w, const float* __restrict__ m2b,
                        float* __restrict__ logits) {
    __shared__ __align__(16) unsigned short sA[64 * 64];
    __shared__ __align__(16) unsigned short sB[512 * 64];
    __shared__ float sRed[2][8][64];
    __shared__ float sMu[64], sRs[64];
    __shared__ float sLp[8][64];
    int bt0 = blockIdx.x * 64;
    int b = bt0 >> 10;
    int tid = threadIdx.x, lane = tid & 63, w = tid >> 6;
    int wm = w >> 2, wn = w & 3;
    int lo = lane & 15, hi = lane >> 4;
    int lr = lane >> 3, sl = lane & 7;
    // A reg-staging (f32 -> bf16 in-kernel)
    int arow = tid >> 3, aslot = tid & 7;
    const float* gA = x + (size_t)(bt0 + arow) * 512 + aslot * 8;
    unsigned short* dAp = sA + arow * 64 + ((aslot ^ (arow & 7)) << 3);
    // B staging via global_load_lds with inverse-swizzled source
    const unsigned short* gB[8]; unsigned short* dB[8];
    #pragma unroll
    for (int g = 0; g < 8; ++g) {
        int brow = w * 64 + g * 8 + lr;   // brow&7 == lr
        gB[g] = M1bf + (size_t)brow * 512 + ((sl ^ lr) << 3);
        dB[g] = sB + (w * 64 + g * 8) * 64;
    }
    f32x4 acc[2][8] = {};
    for (int k0 = 0; k0 < 512; k0 += 64) {
        if (k0) __syncthreads();
        #pragma unroll
        for (int g = 0; g < 8; ++g) GLOAD_LDS16(gB[g] + k0, dB[g]);
        float4 f0 = *(const float4*)(gA + k0);
        float4 f1 = *(const float4*)(gA + k0 + 4);
        bf16x8 pk;
        pk[0] = (short)f2bf(f0.x); pk[1] = (short)f2bf(f0.y);
        pk[2] = (short)f2bf(f0.z); pk[3] = (short)f2bf(f0.w);
        pk[4] = (short)f2bf(f1.x); pk[5] = (short)f2bf(f1.y);
        pk[6] = (short)f2bf(f1.z); pk[7] = (short)f2bf(f1.w);
        *(bf16x8*)dAp = pk;
        __syncthreads();
        #pragma unroll
        for (int kk = 0; kk < 2; ++kk) {
            int slotX = ((kk * 4 + hi) ^ (lo & 7)) << 3;
            bf16x8 a0 = *(const bf16x8*)(sA + (wm * 32 +      lo) * 64 + slotX);
            bf16x8 a1 = *(const bf16x8*)(sA + (wm * 32 + 16 + lo) * 64 + slotX);
            #pragma unroll
            for (int n = 0; n < 8; ++n) {
                bf16x8 bb = *(const bf16x8*)(sB + (wn * 128 + n * 16 + lo) * 64 + slotX);
                acc[0][n] = MFMA(a0, bb, acc[0][n]);
                acc[1][n] = MFMA(a1, bb, acc[1][n]);
            }
        }
    }
    // add cb
    #pragma unroll
    for (int n = 0; n < 8; ++n) {
        float cbv = cb[b * 512 + wn * 128 + n * 16 + lo];
        #pragma unroll
        for (int m = 0; m < 2; ++m)
            #pragma unroll
            for (int r = 0; r < 4; ++r)
                acc[m][n][r] += cbv;
    }
    // LN row stats: per-wave partial over 128 cols, then cross-wave
    #pragma unroll
    for (int m = 0; m < 2; ++m) {
        #pragma unroll
        for (int r = 0; r < 4; ++r) {
            float s1 = 0.f, s2 = 0.f;
            #pragma unroll
            for (int n = 0; n < 8; ++n) { float t = acc[m][n][r]; s1 += t; s2 += t * t; }
            #pragma unroll
            for (int msk = 1; msk < 16; msk <<= 1) {
                s1 += __shfl_xor(s1, msk);
                s2 += __shfl_xor(s2, msk);
            }
            if (lo == 0) {
                int row = wm * 32 + m * 16 + hi * 4 + r;
                sRed[0][w][row] = s1;
                sRed[1][w][row] = s2;
            }
        }
    }
    __syncthreads();
    if (tid < 64) {
        int wmr = tid >> 5;
        float s1 = 0.f, s2 = 0.f;
        #pragma unroll
        for (int q = 0; q < 4; ++q) { s1 += sRed[0][wmr * 4 + q][tid]; s2 += sRed[1][wmr * 4 + q][tid]; }
        float mu = s1 * (1.0f / 512.0f);
        float var = s2 * (1.0f / 512.0f) - mu * mu;
        sMu[tid] = mu;
        sRs[tid] = rsqrtf(var + 1e-5f);
    }
    __syncthreads();
    float gv[8], bv[8], wv[8];
    #pragma unroll
    for (int n = 0; n < 8; ++n) {
        int c = wn * 128 + n * 16 + lo;
        gv[n] = lng[c]; bv[n] = lnb[c]; wv[n] = m2w[c];
    }
    #pragma unroll
    for (int m = 0; m < 2; ++m) {
        #pragma unroll
        for (int r = 0; r < 4; ++r) {
            int row = wm * 32 + m * 16 + hi * 4 + r;
            float mu = sMu[row], rs = sRs[row];
            float lg = 0.f;
            #pragma unroll
            for (int n = 0; n < 8; ++n) {
                float h = tanh_fast((acc[m][n][r] - mu) * rs * gv[n] + bv[n]);
                lg += h * wv[n];
            }
            #pragma unroll
            for (int msk = 1; msk < 16; msk <<= 1) lg += __shfl_xor(lg, msk);
            if (lo == 0) sLp[w][row] = lg;
        }
    }
    __syncthreads();
    if (tid < 64) {
        int wmr = tid >> 5;
        float lg = 0.f;
        #pragma unroll
        for (int q = 0; q < 4; ++q) lg += sLp[wmr * 4 + q][tid];
        logits[bt0 + tid] = lg + m2b[0];
    }
}

// ---------------- softmax over T and context ----------------
__global__ void k_softmax(const float* __restrict__ logits, float* __restrict__ wout) {
    int b = blockIdx.x, tid = threadIdx.x;   // 256 threads, 4 t each
    __shared__ float red[4];
    float4 v = ((const float4*)(logits + b * 1024))[tid];
    float mx = fmaxf(fmaxf(v.x, v.y), fmaxf(v.z, v.w));
    for (int off = 32; off; off >>= 1) mx = fmaxf(mx, __shfl_xor(mx, off));
    if ((tid & 63) == 0) red[tid >> 6] = mx;
    __syncthreads();
    mx = fmaxf(fmaxf(red[0], red[1]), fmaxf(red[2], red[3]));
    float e0 = expf(v.x - mx), e1 = expf(v.y - mx), e2 = expf(v.z - mx), e3 = expf(v.w - mx);
    float sm = e0 + e1 + e2 + e3;
    for (int off = 32; off; off >>= 1) sm += __shfl_xor(sm, off);
    __syncthreads();
    if ((tid & 63) == 0) red[tid >> 6] = sm;
    __syncthreads();
    float inv = 1.0f / (red[0] + red[1] + red[2] + red[3]);
    float4 o; o.x = e0 * inv; o.y = e1 * inv; o.z = e2 * inv; o.w = e3 * inv;
    ((float4*)(wout + b * 1024))[tid] = o;
}

// context[b][d] = sum_t w[b][t] * x[b][t][d]  (atomic partials; ctx pre-zeroed)
__global__ void k_context(const float* __restrict__ x, const float* __restrict__ wts,
                          float* __restrict__ ctx) {
    int b = blockIdx.x, tc = blockIdx.y;
    int tid = threadIdx.x;
    const float* xp = x + ((size_t)b * 1024 + tc * 64) * 512;
    const float* wp = wts + b * 1024 + tc * 64;
    float a0 = 0.f, a1 = 0.f;
    for (int t = 0; t < 64; ++t) {
        float wv = wp[t];
        a0 += wv * xp[(size_t)t * 512 + tid];
        a1 += wv * xp[(size_t)t * 512 + tid + 256];
    }
    atomicAdd(&ctx[b * 512 + tid], a0);
    atomicAdd(&ctx[b * 512 + tid + 256], a1);
}

// ---------------- launch ----------------
extern "C" void kernel_launch(void* const* d_in, const int* in_sizes, int n_in,
                              void* d_out, int out_size, void* d_ws, size_t ws_size,
                              hipStream_t stream) {
    (void)in_sizes; (void)n_in; (void)out_size; (void)ws_size;
    const float* x    = (const float*)d_in[0];
    const float* Went = (const float*)d_in[1];
    const float* bent = (const float*)d_in[2];
    const float* m1w  = (const float*)d_in[3];
    const float* m1b  = (const float*)d_in[4];
    const float* lng  = (const float*)d_in[5];
    const float* lnb  = (const float*)d_in[6];
    const float* m2w  = (const float*)d_in[7];
    const float* m2b  = (const float*)d_in[8];
    float* out = (float*)d_out;            // [0,8192): context ; [8192,24576): attn
    char* ws = (char*)d_ws;

    unsigned short* Abf   = (unsigned short*)(ws);                        // 4 MB
    unsigned short* WT    = (unsigned short*)(ws + 4194304);              // 8 MB
    float* CpL            = (float*)(ws + 12582912);                      // 8 MB
    float* CpR            = (float*)(ws + 20971520);                      // 8 MB
    unsigned short* M1bf  = (unsigned short*)(ws + 29360128);             // 512 KB
    unsigned short* M2t   = (unsigned short*)(ws + 29884416);             // 512 KB
    float* sumx   = (float*)(ws + 30408704);                              // 32 KB
    float* bias2  = (float*)(ws + 30441472);                              // 2 KB
    float* cb     = (float*)(ws + 30443520);                              // 32 KB
    float* logits = (float*)(ws + 30476288);                              // 64 KB

    hipMemsetAsync(sumx, 0, 512 * 16 * sizeof(float), stream);
    hipMemsetAsync(out, 0, 8192 * sizeof(float), stream);

    k_sumx<<<dim3(16, 16), 256, 0, stream>>>(x, sumx);
    k_prepA<<<512, 256, 0, stream>>>(m1w, bent, Abf, bias2);
    k_conv_W<<<dim3(32, 32), 256, 0, stream>>>(Went, WT);
    k_gemm1<<<dim3(8, 4, 8), 512, 0, stream>>>(Abf, WT, CpL, CpR);
    k_reduce8<<<256, 256, 0, stream>>>(CpL, M1bf);
    k_reduce8<<<256, 256, 0, stream>>>(CpR, M2t);
    k_cb<<<dim3(16, 8), 256, 0, stream>>>(sumx, M2t, bias2, m1b, cb);
    k_gemm2<<<256, 512, 0, stream>>>(x, M1bf, cb, lng, lnb, m2w, m2b, logits);
    k_softmax<<<16, 256, 0, stream>>>(logits, out + 8192);
    k_context<<<dim3(16, 16), 256, 0, stream>>>(x, out + 8192, out);
}

// Round 3
// 90.340 us; speedup vs baseline: 1.7561x; 1.0376x over previous
//
#include <hip/hip_runtime.h>
#include <hip/hip_bf16.h>

typedef __attribute__((ext_vector_type(8))) short bf16x8;
typedef __attribute__((ext_vector_type(4))) float f32x4;

__device__ __forceinline__ float bf2f(unsigned short u) {
    union { unsigned int i; float f; } c; c.i = ((unsigned int)u) << 16; return c.f;
}
__device__ __forceinline__ unsigned short f2bf(float f) {
    union { float f; unsigned int i; } c; c.f = f;
    unsigned int x = c.i;
    x += 0x7fffu + ((x >> 16) & 1u);   // round-to-nearest-even
    return (unsigned short)(x >> 16);
}
__device__ __forceinline__ float tanh_fast(float v) {
    float a = fabsf(v);
    a = fminf(a, 15.0f);
    float e = __expf(2.0f * a);
    float t = 1.0f - 2.0f / (e + 1.0f);
    return copysignf(t, v);
}

// async global->LDS, 16B per lane; lptr must be wave-uniform, gptr per-lane
#define GLOAD_LDS16(gp, lp) \
    __builtin_amdgcn_global_load_lds((const __attribute__((address_space(1))) void*)(gp), \
                                     (__attribute__((address_space(3))) void*)(lp), 16, 0, 0)

#define MFMA(a, b, c) __builtin_amdgcn_mfma_f32_16x16x32_bf16((a), (b), (c), 0, 0, 0)

#define SBAR()  __builtin_amdgcn_s_barrier()
#define SCHED0() __builtin_amdgcn_sched_barrier(0)

// ---------------- small reductions ----------------

// sum over t of x -> sumx[b][d] (atomic partials; sumx pre-zeroed)
__global__ void k_sumx(const float* __restrict__ x, float* __restrict__ sumx) {
    int b = blockIdx.x, tc = blockIdx.y;
    int tid = threadIdx.x;
    const float* xp = x + ((size_t)b * 1024 + tc * 64) * 512;
    float a0 = 0.f, a1 = 0.f;
    for (int t = 0; t < 64; ++t) {
        a0 += xp[(size_t)t * 512 + tid];
        a1 += xp[(size_t)t * 512 + tid + 256];
    }
    atomicAdd(&sumx[b * 512 + tid], a0);
    atomicAdd(&sumx[b * 512 + tid + 256], a1);
}

// Abf[i][k] = bf16(m1w[i][k]) (natural order; K index k = e*8+s), fused with
// bias2[i] = sum_k m1w[i,k] * b_ent[(k&7)*512 + (k>>3)]
__global__ void k_prepA(const float* __restrict__ m1w, const float* __restrict__ bent,
                        unsigned short* __restrict__ Abf, float* __restrict__ bias2) {
    int i = blockIdx.x, tid = threadIdx.x;
    const float* row = m1w + (size_t)i * 4096;
    float acc = 0.f;
    #pragma unroll
    for (int q = 0; q < 4; ++q) {
        int col = q * 1024 + tid * 4;
        float4 v = *(const float4*)(row + col);
        ushort4 o;
        o.x = f2bf(v.x); o.y = f2bf(v.y); o.z = f2bf(v.z); o.w = f2bf(v.w);
        *(ushort4*)(Abf + (size_t)i * 4096 + col) = o;
        int e0 = col >> 3, s0 = col & 7;   // col % 4 == 0, so s0 in {0,4}; no e crossing
        acc += v.x * bent[(s0    ) * 512 + e0];
        acc += v.y * bent[(s0 + 1) * 512 + e0];
        acc += v.z * bent[(s0 + 2) * 512 + e0];
        acc += v.w * bent[(s0 + 3) * 512 + e0];
    }
    #pragma unroll
    for (int off = 32; off; off >>= 1) acc += __shfl_xor(acc, off);
    __shared__ float r4[4];
    if ((tid & 63) == 0) r4[tid >> 6] = acc;
    __syncthreads();
    if (tid == 0) bias2[i] = r4[0] + r4[1] + r4[2] + r4[3];
}

// WT[j][k] = bf16(W_ent[(k&7)*512 + (k>>3)][j]); k = e*8+s
__global__ void k_conv_W(const float* __restrict__ W, unsigned short* __restrict__ WT) {
    __shared__ float tile[128][33];
    int e0 = blockIdx.x * 16;
    int j0 = blockIdx.y * 32;
    int tid = threadIdx.x;
    int tx = tid & 31, ty = tid >> 5;
    #pragma unroll
    for (int q = 0; q < 16; ++q) {
        int lk = q * 8 + ty;              // local k = de*8+s, 0..127
        int de = lk >> 3, s = lk & 7;
        int r = s * 512 + e0 + de;
        tile[lk][tx] = W[(size_t)r * 1024 + j0 + tx];
    }
    __syncthreads();
    int j = tid >> 3, ck = (tid & 7) * 16;
    unsigned short* dst = WT + (size_t)(j0 + j) * 4096 + e0 * 8 + ck;
    #pragma unroll
    for (int g = 0; g < 4; ++g) {
        ushort4 o;
        o.x = f2bf(tile[ck + g * 4 + 0][j]);
        o.y = f2bf(tile[ck + g * 4 + 1][j]);
        o.z = f2bf(tile[ck + g * 4 + 2][j]);
        o.w = f2bf(tile[ck + g * 4 + 3][j]);
        *(ushort4*)(dst + g * 4) = o;
    }
}

// ---------------- GEMM1 (split-K=8, pipelined): C[i,j] = sum_k Abf[i,k] WT[j,k] ----------------
// tile 64x256, 8 waves (2m x 4n), BK=64, XOR-swizzled LDS, double-buffered, counted vmcnt.
// left j-tiles (by<2) store C partials; right (by>=2) store C^T partials (swapped mfma).
__launch_bounds__(512, 2)
__global__ void k_gemm1(const unsigned short* __restrict__ Abf,
                        const unsigned short* __restrict__ WT,
                        float* __restrict__ CpL, float* __restrict__ CpR) {
    __shared__ __align__(16) unsigned short sA[2][64 * 64];
    __shared__ __align__(16) unsigned short sB[2][256 * 64];
    int i0 = blockIdx.x * 64;
    int j0 = blockIdx.y * 256;
    int kbase = blockIdx.z * 512;
    int tid = threadIdx.x, lane = tid & 63, w = tid >> 6;
    int wm = w >> 2, wn = w & 3;
    int lr = lane >> 3, sl = lane & 7;
    int lo = lane & 15, hi = lane >> 4;
    int arow = w * 8 + lr;  // arow&7 == lr
    const unsigned short* gA = Abf + (size_t)(i0 + arow) * 4096 + kbase + ((sl ^ lr) << 3);
    const unsigned short* gB0 = WT + (size_t)(j0 + w * 32 + 0 * 8 + lr) * 4096 + kbase + ((sl ^ lr) << 3);
    const unsigned short* gB1 = WT + (size_t)(j0 + w * 32 + 1 * 8 + lr) * 4096 + kbase + ((sl ^ lr) << 3);
    const unsigned short* gB2 = WT + (size_t)(j0 + w * 32 + 2 * 8 + lr) * 4096 + kbase + ((sl ^ lr) << 3);
    const unsigned short* gB3 = WT + (size_t)(j0 + w * 32 + 3 * 8 + lr) * 4096 + kbase + ((sl ^ lr) << 3);
    bool left = (blockIdx.y < 2);
    f32x4 acc[2][4] = {};

#define G1_STAGE(tt, bufn)                                                    \
    do {                                                                      \
        int koff = (tt) * 64;                                                 \
        GLOAD_LDS16(gA + koff, &sA[bufn][w * 8 * 64]);                        \
        GLOAD_LDS16(gB0 + koff, &sB[bufn][(w * 32 + 0) * 64]);                \
        GLOAD_LDS16(gB1 + koff, &sB[bufn][(w * 32 + 8) * 64]);                \
        GLOAD_LDS16(gB2 + koff, &sB[bufn][(w * 32 + 16) * 64]);               \
        GLOAD_LDS16(gB3 + koff, &sB[bufn][(w * 32 + 24) * 64]);               \
        SCHED0();                                                             \
    } while (0)

    G1_STAGE(0, 0);
    #pragma unroll
    for (int t = 0; t < 8; ++t) {
        int buf = t & 1;
        if (t < 7) {
            G1_STAGE(t + 1, buf ^ 1);
            asm volatile("s_waitcnt vmcnt(5)" ::: "memory");
        } else {
            asm volatile("s_waitcnt vmcnt(0)" ::: "memory");
        }
        SCHED0(); SBAR(); SCHED0();
        __builtin_amdgcn_s_setprio(1);
        #pragma unroll
        for (int kk = 0; kk < 2; ++kk) {
            int slotX = ((kk * 4 + hi) ^ (lo & 7)) << 3;
            bf16x8 a0 = *(const bf16x8*)(&sA[buf][(wm * 32 +      lo) * 64 + slotX]);
            bf16x8 a1 = *(const bf16x8*)(&sA[buf][(wm * 32 + 16 + lo) * 64 + slotX]);
            #pragma unroll
            for (int n = 0; n < 4; ++n) {
                bf16x8 bb = *(const bf16x8*)(&sB[buf][(wn * 64 + n * 16 + lo) * 64 + slotX]);
                if (left) {
                    acc[0][n] = MFMA(a0, bb, acc[0][n]);
                    acc[1][n] = MFMA(a1, bb, acc[1][n]);
                } else {
                    acc[0][n] = MFMA(bb, a0, acc[0][n]);
                    acc[1][n] = MFMA(bb, a1, acc[1][n]);
                }
            }
        }
        __builtin_amdgcn_s_setprio(0);
        if (t < 7) { SCHED0(); SBAR(); SCHED0(); }
    }
#undef G1_STAGE

    int ksoff = blockIdx.z * 262144;
    if (left) {
        #pragma unroll
        for (int m = 0; m < 2; ++m) {
            int ib = i0 + wm * 32 + m * 16 + hi * 4;
            #pragma unroll
            for (int n = 0; n < 4; ++n) {
                int j = j0 + wn * 64 + n * 16 + lo;
                #pragma unroll
                for (int r = 0; r < 4; ++r)
                    CpL[ksoff + (ib + r) * 512 + j] = acc[m][n][r];
            }
        }
    } else {
        #pragma unroll
        for (int m = 0; m < 2; ++m) {
            int ic = i0 + wm * 32 + m * 16 + lo;
            #pragma unroll
            for (int n = 0; n < 4; ++n) {
                int db = j0 - 512 + wn * 64 + n * 16 + hi * 4;
                #pragma unroll
                for (int r = 0; r < 4; ++r)
                    CpR[ksoff + (db + r) * 512 + ic] = acc[m][n][r];
            }
        }
    }
}

// sum 8 split-K partials -> bf16; blocks 0..255 -> M1bf, 256..511 -> M2t
__global__ void k_reduce(const float* __restrict__ CpL, const float* __restrict__ CpR,
                         unsigned short* __restrict__ M1bf, unsigned short* __restrict__ M2t) {
    int bx = blockIdx.x;
    const float* Cp = (bx < 256) ? CpL : CpR;
    unsigned short* ob = (bx < 256) ? M1bf : M2t;
    int gid = (bx & 255) * 256 + threadIdx.x;   // x4 floats
    float4 s = ((const float4*)Cp)[gid];
    #pragma unroll
    for (int ks = 1; ks < 8; ++ks) {
        float4 t = ((const float4*)Cp)[ks * 65536 + gid];
        s.x += t.x; s.y += t.y; s.z += t.z; s.w += t.w;
    }
    ushort4 o;
    o.x = f2bf(s.x); o.y = f2bf(s.y); o.z = f2bf(s.z); o.w = f2bf(s.w);
    ((ushort4*)ob)[gid] = o;
}

// cb[b][i] = (1/T) * sum_d sumx[b][d]*M2t[d][i] + bias2[i] + m1b[i]
__global__ void k_cb(const float* __restrict__ sumx, const unsigned short* __restrict__ M2t,
                     const float* __restrict__ bias2, const float* __restrict__ m1b,
                     float* __restrict__ cbo) {
    int b = blockIdx.x, i0 = blockIdx.y * 64;
    int tid = threadIdx.x;
    int il = tid & 63, dq = tid >> 6;
    const float* sx = sumx + b * 512 + dq * 128;
    const unsigned short* mp = M2t + (size_t)dq * 128 * 512 + i0 + il;
    float acc = 0.f;
    #pragma unroll 4
    for (int dd = 0; dd < 128; ++dd)
        acc += sx[dd] * bf2f(mp[(size_t)dd * 512]);
    __shared__ float sPart[4][64];
    sPart[dq][il] = acc;
    __syncthreads();
    if (tid < 64) {
        float v = sPart[0][tid] + sPart[1][tid] + sPart[2][tid] + sPart[3][tid];
        cbo[b * 512 + i0 + tid] = v * (1.0f / 1024.0f) + bias2[i0 + tid] + m1b[i0 + tid];
    }
}

// ---------------- GEMM2 + fused LN/tanh/logit (pipelined) ----------------
// y[bt,i] = sum_d x[bt,d]*M1[i,d] + cb[b,i]; LN over i; tanh; logit = h . m2w + m2b
// tile 64 x 512(full N), 8 waves (2m x 4n), BK=64, double-buffered, counted vmcnt.
// A reg-staged from f32 x (T14 split: load-early, ds_write-late); B via global_load_lds.
__launch_bounds__(512)
__global__ void k_gemm2(const float* __restrict__ x,
                        const unsigned short* __restrict__ M1bf,
                        const float* __restrict__ cb,
                        const float* __restrict__ lng, const float* __restrict__ lnb,
                        const float* __restrict__ m2w, const float* __restrict__ m2b,
                        float* __restrict__ logits) {
    __shared__ __align__(16) unsigned short sA[2][64 * 64];
    __shared__ __align__(16) unsigned short sB[2][512 * 64];
    __shared__ float sRed[2][8][64];
    __shared__ float sMu[64], sRs[64];
    __shared__ float sLp[8][64];
    int bt0 = blockIdx.x * 64;
    int b = bt0 >> 10;
    int tid = threadIdx.x, lane = tid & 63, w = tid >> 6;
    int wm = w >> 2, wn = w & 3;
    int lo = lane & 15, hi = lane >> 4;
    int lr = lane >> 3, sl = lane & 7;
    // A reg-staging: thread covers row arow, 8 cols at slot aslot
    int arow = tid >> 3, aslot = tid & 7;
    const float* gA = x + (size_t)(bt0 + arow) * 512 + aslot * 8;
    int aoff = arow * 64 + ((aslot ^ (arow & 7)) << 3);
    // B staging via global_load_lds with inverse-swizzled source
    const unsigned short* gB[8];
    #pragma unroll
    for (int g = 0; g < 8; ++g)
        gB[g] = M1bf + (size_t)(w * 64 + g * 8 + lr) * 512 + ((sl ^ lr) << 3);
    float4 pf0, pf1;
    f32x4 acc[2][8] = {};

#define G2_ISSUE(tt, bufn)                                                    \
    do {                                                                      \
        pf0 = *(const float4*)(gA + (tt) * 64);                               \
        pf1 = *(const float4*)(gA + (tt) * 64 + 4);                           \
        SCHED0();                                                             \
        _Pragma("unroll")                                                     \
        for (int g = 0; g < 8; ++g)                                           \
            GLOAD_LDS16(gB[g] + (tt) * 64, &sB[bufn][(w * 64 + g * 8) * 64]); \
        SCHED0();                                                             \
    } while (0)

#define G2_AWRITE(bufn)                                                      \
    do {                                                                     \
        bf16x8 pk;                                                           \
        pk[0] = (short)f2bf(pf0.x); pk[1] = (short)f2bf(pf0.y);              \
        pk[2] = (short)f2bf(pf0.z); pk[3] = (short)f2bf(pf0.w);              \
        pk[4] = (short)f2bf(pf1.x); pk[5] = (short)f2bf(pf1.y);              \
        pk[6] = (short)f2bf(pf1.z); pk[7] = (short)f2bf(pf1.w);              \
        *(bf16x8*)(&sA[bufn][aoff]) = pk;                                    \
    } while (0)

    // prologue: stage tile 0
    G2_ISSUE(0, 0);
    asm volatile("s_waitcnt vmcnt(8)" ::: "memory");   // x regs back; B0 in flight
    SCHED0();
    G2_AWRITE(0);
    asm volatile("s_waitcnt lgkmcnt(0)" ::: "memory");
    SCHED0();

    #pragma unroll
    for (int t = 0; t < 8; ++t) {
        int buf = t & 1;
        if (t < 7) {
            G2_ISSUE(t + 1, buf ^ 1);
            asm volatile("s_waitcnt vmcnt(10)" ::: "memory");   // B_t landed
        } else {
            asm volatile("s_waitcnt vmcnt(0)" ::: "memory");
        }
        SCHED0(); SBAR(); SCHED0();
        __builtin_amdgcn_s_setprio(1);
        #pragma unroll
        for (int kk = 0; kk < 2; ++kk) {
            int slotX = ((kk * 4 + hi) ^ (lo & 7)) << 3;
            bf16x8 a0 = *(const bf16x8*)(&sA[buf][(wm * 32 +      lo) * 64 + slotX]);
            bf16x8 a1 = *(const bf16x8*)(&sA[buf][(wm * 32 + 16 + lo) * 64 + slotX]);
            #pragma unroll
            for (int n = 0; n < 8; ++n) {
                bf16x8 bb = *(const bf16x8*)(&sB[buf][(wn * 128 + n * 16 + lo) * 64 + slotX]);
                acc[0][n] = MFMA(a0, bb, acc[0][n]);
                acc[1][n] = MFMA(a1, bb, acc[1][n]);
            }
        }
        __builtin_amdgcn_s_setprio(0);
        if (t < 7) {
            asm volatile("s_waitcnt vmcnt(8)" ::: "memory");    // x_{t+1} regs back
            SCHED0();
            G2_AWRITE(buf ^ 1);
            asm volatile("s_waitcnt lgkmcnt(0)" ::: "memory");
            SCHED0(); SBAR(); SCHED0();
        }
    }
#undef G2_ISSUE
#undef G2_AWRITE

    // add cb
    #pragma unroll
    for (int n = 0; n < 8; ++n) {
        float cbv = cb[b * 512 + wn * 128 + n * 16 + lo];
        #pragma unroll
        for (int m = 0; m < 2; ++m)
            #pragma unroll
            for (int r = 0; r < 4; ++r)
                acc[m][n][r] += cbv;
    }
    // LN row stats: per-wave partial over 128 cols, then cross-wave
    #pragma unroll
    for (int m = 0; m < 2; ++m) {
        #pragma unroll
        for (int r = 0; r < 4; ++r) {
            float s1 = 0.f, s2 = 0.f;
            #pragma unroll
            for (int n = 0; n < 8; ++n) { float t = acc[m][n][r]; s1 += t; s2 += t * t; }
            #pragma unroll
            for (int msk = 1; msk < 16; msk <<= 1) {
                s1 += __shfl_xor(s1, msk);
                s2 += __shfl_xor(s2, msk);
            }
            if (lo == 0) {
                int row = wm * 32 + m * 16 + hi * 4 + r;
                sRed[0][w][row] = s1;
                sRed[1][w][row] = s2;
            }
        }
    }
    __syncthreads();
    if (tid < 64) {
        int wmr = tid >> 5;
        float s1 = 0.f, s2 = 0.f;
        #pragma unroll
        for (int q = 0; q < 4; ++q) { s1 += sRed[0][wmr * 4 + q][tid]; s2 += sRed[1][wmr * 4 + q][tid]; }
        float mu = s1 * (1.0f / 512.0f);
        float var = s2 * (1.0f / 512.0f) - mu * mu;
        sMu[tid] = mu;
        sRs[tid] = rsqrtf(var + 1e-5f);
    }
    __syncthreads();
    float gv[8], bv[8], wv[8];
    #pragma unroll
    for (int n = 0; n < 8; ++n) {
        int c = wn * 128 + n * 16 + lo;
        gv[n] = lng[c]; bv[n] = lnb[c]; wv[n] = m2w[c];
    }
    #pragma unroll
    for (int m = 0; m < 2; ++m) {
        #pragma unroll
        for (int r = 0; r < 4; ++r) {
            int row = wm * 32 + m * 16 + hi * 4 + r;
            float mu = sMu[row], rs = sRs[row];
            float lg = 0.f;
            #pragma unroll
            for (int n = 0; n < 8; ++n) {
                float h = tanh_fast((acc[m][n][r] - mu) * rs * gv[n] + bv[n]);
                lg += h * wv[n];
            }
            #pragma unroll
            for (int msk = 1; msk < 16; msk <<= 1) lg += __shfl_xor(lg, msk);
            if (lo == 0) sLp[w][row] = lg;
        }
    }
    __syncthreads();
    if (tid < 64) {
        int wmr = tid >> 5;
        float lg = 0.f;
        #pragma unroll
        for (int q = 0; q < 4; ++q) lg += sLp[wmr * 4 + q][tid];
        logits[bt0 + tid] = lg + m2b[0];
    }
}

// ---------------- softmax over T and context ----------------
__global__ void k_softmax(const float* __restrict__ logits, float* __restrict__ wout) {
    int b = blockIdx.x, tid = threadIdx.x;   // 256 threads, 4 t each
    __shared__ float red[4];
    float4 v = ((const float4*)(logits + b * 1024))[tid];
    float mx = fmaxf(fmaxf(v.x, v.y), fmaxf(v.z, v.w));
    for (int off = 32; off; off >>= 1) mx = fmaxf(mx, __shfl_xor(mx, off));
    if ((tid & 63) == 0) red[tid >> 6] = mx;
    __syncthreads();
    mx = fmaxf(fmaxf(red[0], red[1]), fmaxf(red[2], red[3]));
    float e0 = expf(v.x - mx), e1 = expf(v.y - mx), e2 = expf(v.z - mx), e3 = expf(v.w - mx);
    float sm = e0 + e1 + e2 + e3;
    for (int off = 32; off; off >>= 1) sm += __shfl_xor(sm, off);
    __syncthreads();
    if ((tid & 63) == 0) red[tid >> 6] = sm;
    __syncthreads();
    float inv = 1.0f / (red[0] + red[1] + red[2] + red[3]);
    float4 o; o.x = e0 * inv; o.y = e1 * inv; o.z = e2 * inv; o.w = e3 * inv;
    ((float4*)(wout + b * 1024))[tid] = o;
}

// context[b][d] = sum_t w[b][t] * x[b][t][d]  (atomic partials; ctx pre-zeroed)
__global__ void k_context(const float* __restrict__ x, const float* __restrict__ wts,
                          float* __restrict__ ctx) {
    int b = blockIdx.x, tc = blockIdx.y;
    int tid = threadIdx.x;
    const float* xp = x + ((size_t)b * 1024 + tc * 64) * 512;
    const float* wp = wts + b * 1024 + tc * 64;
    float a0 = 0.f, a1 = 0.f;
    for (int t = 0; t < 64; ++t) {
        float wv = wp[t];
        a0 += wv * xp[(size_t)t * 512 + tid];
        a1 += wv * xp[(size_t)t * 512 + tid + 256];
    }
    atomicAdd(&ctx[b * 512 + tid], a0);
    atomicAdd(&ctx[b * 512 + tid + 256], a1);
}

// ---------------- launch ----------------
extern "C" void kernel_launch(void* const* d_in, const int* in_sizes, int n_in,
                              void* d_out, int out_size, void* d_ws, size_t ws_size,
                              hipStream_t stream) {
    (void)in_sizes; (void)n_in; (void)out_size; (void)ws_size;
    const float* x    = (const float*)d_in[0];
    const float* Went = (const float*)d_in[1];
    const float* bent = (const float*)d_in[2];
    const float* m1w  = (const float*)d_in[3];
    const float* m1b  = (const float*)d_in[4];
    const float* lng  = (const float*)d_in[5];
    const float* lnb  = (const float*)d_in[6];
    const float* m2w  = (const float*)d_in[7];
    const float* m2b  = (const float*)d_in[8];
    float* out = (float*)d_out;            // [0,8192): context ; [8192,24576): attn
    char* ws = (char*)d_ws;

    unsigned short* Abf   = (unsigned short*)(ws);                        // 4 MB
    unsigned short* WT    = (unsigned short*)(ws + 4194304);              // 8 MB
    float* CpL            = (float*)(ws + 12582912);                      // 8 MB
    float* CpR            = (float*)(ws + 20971520);                      // 8 MB
    unsigned short* M1bf  = (unsigned short*)(ws + 29360128);             // 512 KB
    unsigned short* M2t   = (unsigned short*)(ws + 29884416);             // 512 KB
    float* sumx   = (float*)(ws + 30408704);                              // 32 KB
    float* bias2  = (float*)(ws + 30441472);                              // 2 KB
    float* cb     = (float*)(ws + 30443520);                              // 32 KB
    float* logits = (float*)(ws + 30476288);                              // 64 KB

    hipMemsetAsync(sumx, 0, 512 * 16 * sizeof(float), stream);
    hipMemsetAsync(out, 0, 8192 * sizeof(float), stream);

    k_sumx<<<dim3(16, 16), 256, 0, stream>>>(x, sumx);
    k_prepA<<<512, 256, 0, stream>>>(m1w, bent, Abf, bias2);
    k_conv_W<<<dim3(32, 32), 256, 0, stream>>>(Went, WT);
    k_gemm1<<<dim3(8, 4, 8), 512, 0, stream>>>(Abf, WT, CpL, CpR);
    k_reduce<<<512, 256, 0, stream>>>(CpL, CpR, M1bf, M2t);
    k_cb<<<dim3(16, 8), 256, 0, stream>>>(sumx, M2t, bias2, m1b, cb);
    k_gemm2<<<256, 512, 0, stream>>>(x, M1bf, cb, lng, lnb, m2w, m2b, logits);
    k_softmax<<<16, 256, 0, stream>>>(logits, out + 8192);
    k_context<<<dim3(16, 16), 256, 0, stream>>>(x, out + 8192, out);
}